// Round 2
// baseline (472.541 us; speedup 1.0000x reference)
//
#include <hip/hip_runtime.h>

// Shapes fixed by the reference: D=128 features, E=128 edges, B=4096 batch.
constexpr int D    = 128;
constexpr int E    = 128;
constexpr int BB   = 4096;
constexpr int ROWS = 8;      // batch rows per prep block

// NO workspace use. Scratch lives inside d_out (race-free by construction):
//   v[b,0:D]  at out[(0*BB + b)*D ...]   -- the e=0 slice, column b
//   c[b]      at out[(1*BB + b)*D]       -- first elem of e=1 slice, column b
// att_main block b reads only its own column's scratch before overwriting it
// with the final output; no other block touches column b.

// ---------------------------------------------------------------------------
// prep: m_i = T[b,:]@W^T + bias ; v[b,:] = m_i@W ; c[b] = m_i . bias
// 512 blocks x 256 threads, 8 batch rows per block. W staged in padded LDS.
// ---------------------------------------------------------------------------
__global__ __launch_bounds__(256) void prep_kernel(
    const float* __restrict__ T, const float* __restrict__ W,
    const float* __restrict__ bias, float* out)
{
    __shared__ float Wl[D][D + 1];   // +1 pad: conflict-free column reads
    __shared__ float Tl[ROWS][D];
    __shared__ float biasl[D];
    __shared__ float m[2][D];
    __shared__ float partial[4];

    const int t  = threadIdx.x;
    const int b0 = blockIdx.x * ROWS;

    for (int i = t; i < D * D; i += 256)
        Wl[i >> 7][i & 127] = W[i];
    for (int i = t; i < ROWS * D; i += 256)
        Tl[i >> 7][i & 127] = T[b0 * D + i];
    if (t < D) biasl[t] = bias[t];
    __syncthreads();

    const int half = t >> 7;   // 0 or 1 -> which of the 2 concurrent rows
    const int lid  = t & 127;

    for (int pair = 0; pair < ROWS / 2; ++pair) {
        const int bl = pair * 2 + half;
        // phase 1: m_i[f] = sum_d T[b,d] * W[f,d] + bias[f]   (f = lid)
        float acc = biasl[lid];
        for (int d = 0; d < D; ++d) acc += Tl[bl][d] * Wl[lid][d];
        m[half][lid] = acc;
        // c partial: m_i[f] * bias[f], wave-reduced (64 lanes), 2 waves/half
        float pc = acc * biasl[lid];
        #pragma unroll
        for (int msk = 32; msk >= 1; msk >>= 1) pc += __shfl_xor(pc, msk);
        if ((t & 63) == 0) partial[t >> 6] = pc;
        __syncthreads();
        // phase 2: v[b,d] = sum_f m_i[f] * W[f,d]             (d = lid)
        float vacc = 0.f;
        for (int f = 0; f < D; ++f) vacc += m[half][f] * Wl[f][lid];
        out[(size_t)(b0 + bl) * D + lid] = vacc;                 // v slot (e=0)
        if (lid == 0)
            out[(size_t)(BB + b0 + bl) * D] =
                partial[2 * half] + partial[2 * half + 1];       // c slot (e=1)
        __syncthreads();   // protects m[]/partial[] before next pair
    }
}

// ---------------------------------------------------------------------------
// main: one block per batch index b. 256 threads = 8 edge-groups x 32 lanes.
// Lane holds float4 of S[e,b,:]; full E x D slice register-resident (64 VGPR).
// e_ij[e] = S[e,b,:].v[b,:] + c[b]; sum over e in double; scale + store.
// ---------------------------------------------------------------------------
__global__ __launch_bounds__(256) void att_main(
    const float* __restrict__ S, float* out)
{
    const int b  = blockIdx.x;
    const int t  = threadIdx.x;
    const int lc = t & 31;   // float4 chunk within row (d = lc*4 .. lc*4+3)
    const int eb = t >> 5;   // 0..7, edge within iteration group

    __shared__ float sc[E];
    __shared__ float inv_s;

    const float4* Sp = (const float4*)S;
    const float4  v4 = ((const float4*)(out + (size_t)b * D))[lc]; // v scratch
    const float   c  = out[(size_t)(BB + b) * D];                  // c scratch

    // Load the whole E x D slice for this b into registers. Fully coalesced:
    // 64 lanes x 16B = 1KB per wave instruction; 16 independent loads in flight.
    float4 s[16];
    #pragma unroll
    for (int i = 0; i < 16; ++i) {
        const int e = i * 8 + eb;
        s[i] = Sp[((size_t)e * BB + b) * 32 + lc];
    }

    // Scores: per-lane dot4, butterfly over the 32 lanes of the d-dimension.
    #pragma unroll
    for (int i = 0; i < 16; ++i) {
        float p = s[i].x * v4.x + s[i].y * v4.y + s[i].z * v4.z + s[i].w * v4.w;
        #pragma unroll
        for (int msk = 16; msk >= 1; msk >>= 1) p += __shfl_xor(p, msk);
        if (lc == 0) sc[i * 8 + eb] = p + c;
    }
    __syncthreads();

    // Sum over the 128 edges in double (cancellation-safe), one wave.
    if (t < 64) {
        double d0 = (double)sc[t] + (double)sc[t + 64];
        #pragma unroll
        for (int msk = 32; msk >= 1; msk >>= 1) d0 += __shfl_xor(d0, msk);
        if (t == 0) inv_s = (float)(1.0 / d0);
    }
    __syncthreads();

    const float inv = inv_s;
    #pragma unroll
    for (int i = 0; i < 16; ++i) {
        const int e = i * 8 + eb;
        const float w = sc[e] * inv;      // LDS broadcast within group
        float4 o;
        o.x = s[i].x * w; o.y = s[i].y * w;
        o.z = s[i].z * w; o.w = s[i].w * w;
        ((float4*)out)[((size_t)e * BB + b) * 32 + lc] = o;
    }
}

extern "C" void kernel_launch(void* const* d_in, const int* in_sizes, int n_in,
                              void* d_out, int out_size, void* d_ws, size_t ws_size,
                              hipStream_t stream) {
    // d_in: [0]=true_batch_size(int,1) [1]=T[B,D] [2]=S[E,B,D] [3]=W[D,D] [4]=b[D]
    const float* T    = (const float*)d_in[1];
    const float* S    = (const float*)d_in[2];
    const float* W    = (const float*)d_in[3];
    const float* bias = (const float*)d_in[4];
    float* out        = (float*)d_out;

    prep_kernel<<<BB / ROWS, 256, 0, stream>>>(T, W, bias, out);
    att_main<<<BB, 256, 0, stream>>>(S, out);
}